// Round 7
// baseline (148.634 us; speedup 1.0000x reference)
//
#include <hip/hip_runtime.h>
#include <hip/hip_bf16.h>

#define NB 4
#define NC 128
#define NT 64
#define NHW 1024
#define HHW 512            // hw columns per k_energy block (half of 1024)
#define KC2 64             // fp32 k-elements per chunk
#define NCH2 (HHW / KC2)   // 8 chunks
#define XS2 68             // LDS row stride in shorts (136 B): reads/writes <=2-way

typedef __attribute__((ext_vector_type(8))) short short8_t;
typedef __attribute__((ext_vector_type(4))) short short4_t;
typedef __attribute__((ext_vector_type(4))) float float4_t;

// float4 -> 4 bf16 (RNE)
__device__ __forceinline__ short4_t cvt4(const float4& v) {
    short4_t o;
    o[0] = __builtin_bit_cast(short, __float2bfloat16(v.x));
    o[1] = __builtin_bit_cast(short, __float2bfloat16(v.y));
    o[2] = __builtin_bit_cast(short, __float2bfloat16(v.z));
    o[3] = __builtin_bit_cast(short, __float2bfloat16(v.w));
    return o;
}

// ---------------------------------------------------------------------------
// Kernel 1: partial energy — streaming-regime schedule.
// grid = NB*NC*2 = 1024; block (bc, half): part[bid][t][s] =
//   sum_{hw in half} x[bc,t,hw]*y[bc,s,hw]   (bf16 MFMA, fp32 accum).
// 4 blocks/CU (rolling, phase-diverse). Depth-2 register pipeline: chunk
// ch+2's global loads are issued during chunk ch -> ~2 chunks of slack
// before the ds_write consumes them; VMEM queue never drains at barriers.
// x-loads and y-loads grouped into separate phases (two far-apart streams
// are not interleaved instruction-by-instruction), pinned by sched_barrier.
// ---------------------------------------------------------------------------
__global__ __launch_bounds__(256, 4) void k_energy(
    const float* __restrict__ x, const float* __restrict__ y,
    float* __restrict__ part)
{
    __shared__ __align__(16) short Xs[NT * XS2];   // 8.7 KB
    __shared__ __align__(16) short Ys[NT * XS2];   // 8.7 KB
    const int bc = blockIdx.x >> 1, half = blockIdx.x & 1;
    const float* xb = x + (size_t)bc * NT * NHW + half * HHW;
    const float* yb = y + (size_t)bc * NT * NHW + half * HHW;
    const int tid = threadIdx.x;
    const int lane = tid & 63, w = tid >> 6;
    const int r = lane & 15, g = lane >> 4;

    // staging map: f = tid + 256*it (it<4) -> row = f>>4 (0..63), unit = f&15
    // 16 lanes x 16B = 256B contiguous per row segment.
    float4 px[2][4], py[2][4];

    #define LOADX(s, ch)                                                      \
        _Pragma("unroll")                                                     \
        for (int it = 0; it < 4; ++it) {                                      \
            const int f = tid + it * 256;                                     \
            px[s][it] = *(const float4*)(xb + (size_t)(f >> 4) * NHW +        \
                                         (ch) * KC2 + (f & 15) * 4);          \
        }
    #define LOADY(s, ch)                                                      \
        _Pragma("unroll")                                                     \
        for (int it = 0; it < 4; ++it) {                                      \
            const int f = tid + it * 256;                                     \
            py[s][it] = *(const float4*)(yb + (size_t)(f >> 4) * NHW +        \
                                         (ch) * KC2 + (f & 15) * 4);          \
        }

    float4_t acc[4];
    #pragma unroll
    for (int ct = 0; ct < 4; ++ct)
        #pragma unroll
        for (int j = 0; j < 4; ++j) acc[ct][j] = 0.f;

    // prologue: chunks 0 and 1 in flight (grouped x-phase, then y-phase)
    LOADX(0, 0); LOADX(1, 1);
    __builtin_amdgcn_sched_barrier(0);
    LOADY(0, 0); LOADY(1, 1);
    __builtin_amdgcn_sched_barrier(0);

    #pragma unroll
    for (int ch = 0; ch < NCH2; ++ch) {
        const int s = ch & 1;
        __syncthreads();               // prev chunk's MFMA reads done
        #pragma unroll
        for (int it = 0; it < 4; ++it) {
            const int f = tid + it * 256;
            const int row = f >> 4, u = f & 15;
            *(short4_t*)(&Xs[row * XS2 + u * 4]) = cvt4(px[s][it]);
        }
        #pragma unroll
        for (int it = 0; it < 4; ++it) {
            const int f = tid + it * 256;
            const int row = f >> 4, u = f & 15;
            *(short4_t*)(&Ys[row * XS2 + u * 4]) = cvt4(py[s][it]);
        }
        __syncthreads();               // tile ready
        if (ch + 2 < NCH2) {           // refill the just-consumed register set
            LOADX(s, ch + 2);
            __builtin_amdgcn_sched_barrier(0);
            LOADY(s, ch + 2);
            __builtin_amdgcn_sched_barrier(0);
        }
        #pragma unroll
        for (int kk = 0; kk < 2; ++kk) {
            const short8_t a =
                *(const short8_t*)(&Xs[(16 * w + r) * XS2 + kk * 32 + g * 8]);
            #pragma unroll
            for (int ct = 0; ct < 4; ++ct) {
                const short8_t b =
                    *(const short8_t*)(&Ys[(16 * ct + r) * XS2 + kk * 32 + g * 8]);
                acc[ct] = __builtin_amdgcn_mfma_f32_16x16x32_bf16(a, b, acc[ct], 0, 0, 0);
            }
        }
    }
    #undef LOADX
    #undef LOADY

    // C/D layout (m89-verified): col = lane&15, row = (lane>>4)*4 + reg
    float* pb_out = part + (size_t)blockIdx.x * (NT * NT);
    #pragma unroll
    for (int ct = 0; ct < 4; ++ct)
        #pragma unroll
        for (int reg = 0; reg < 4; ++reg)
            pb_out[(16 * w + g * 4 + reg) * NT + 16 * ct + r] = acc[ct][reg];
}

// ---------------------------------------------------------------------------
// Kernel 2: reduce 256 partials per (b,t,s), row-softmax of (rowmax - e).
// grid = NB*NT blocks x 256 threads (4 slices); LDS reduce; wave 0 softmax.
// softmax(max-e) stabilized: p_s = exp(min_e - e_s), normalize.
// ---------------------------------------------------------------------------
__global__ void k_softmax(const float* __restrict__ part, float* __restrict__ att)
{
    const int b = blockIdx.x >> 6;
    const int t = blockIdx.x & 63;
    const int s = threadIdx.x & 63;
    const int sl = threadIdx.x >> 6;   // 0..3
    __shared__ float red[4][64];

    const float* p = part + (size_t)b * 256 * (NT * NT) + t * NT + s;
    float e = 0.f;
    #pragma unroll 8
    for (int k = sl; k < 256; k += 4)
        e += p[(size_t)k * (NT * NT)];
    red[sl][s] = e;
    __syncthreads();
    if (threadIdx.x < 64) {
        e = red[0][s] + red[1][s] + red[2][s] + red[3][s];
        float mn = e;
        #pragma unroll
        for (int off = 32; off; off >>= 1) mn = fminf(mn, __shfl_xor(mn, off));
        float pv = expf(mn - e);
        float sum = pv;
        #pragma unroll
        for (int off = 32; off; off >>= 1) sum += __shfl_xor(sum, off);
        att[(size_t)blockIdx.x * NT + s] = pv / sum;
    }
}

// ---------------------------------------------------------------------------
// Kernel 3: out[b,c,t,hw] = x[b,c,t,hw] + scale * sum_s A[b,t,s]*y[b,c,s,hw]
// (unchanged — compute-rich streaming, the regime k_energy now copies)
// ---------------------------------------------------------------------------
#define K3_SY 132
#define K3_SA 68
__global__ __launch_bounds__(256, 3) void k_out(
    const float* __restrict__ x, const float* __restrict__ y,
    const float* __restrict__ att, const float* __restrict__ scale_p,
    float* __restrict__ out)
{
    __shared__ float As[NT][K3_SA];   // As[s][t]
    __shared__ float Ys[NT][K3_SY];
    const int bc   = blockIdx.x >> 1;
    const int half = blockIdx.x & 1;
    const int b    = bc >> 7;
    const float scale = scale_p[0];
    const float* xb = x + (size_t)bc * NT * NHW + half * 512;
    const float* yb = y + (size_t)bc * NT * NHW + half * 512;
    float*       ob = out + (size_t)bc * NT * NHW + half * 512;
    const int tid = threadIdx.x;

    #pragma unroll
    for (int it = 0; it < 16; ++it) {
        int f = tid + it * 256;
        int t = f >> 6, s = f & 63;
        As[s][t] = att[((size_t)b * NT + t) * NT + s];
    }

    const int col = (tid & 31) * 4;
    const int g   = tid >> 5;

    for (int ch = 0; ch < 4; ++ch) {
        __syncthreads();
        #pragma unroll
        for (int it = 0; it < 8; ++it) {
            int f   = tid + it * 256;
            int row = f >> 5;
            int c4  = f & 31;
            *(float4*)(&Ys[row][c4 * 4]) =
                *(const float4*)(yb + (size_t)row * NHW + ch * 128 + c4 * 4);
        }
        __syncthreads();

        float4 acc[8] = {};
        #pragma unroll 4
        for (int s = 0; s < NT; ++s) {
            float4 yv = *(const float4*)(&Ys[s][col]);
            float4 al = *(const float4*)(&As[s][8 * g]);
            float4 ah = *(const float4*)(&As[s][8 * g + 4]);
            #define FMA4(A, S) \
                A.x = fmaf(S, yv.x, A.x); A.y = fmaf(S, yv.y, A.y); \
                A.z = fmaf(S, yv.z, A.z); A.w = fmaf(S, yv.w, A.w);
            FMA4(acc[0], al.x) FMA4(acc[1], al.y)
            FMA4(acc[2], al.z) FMA4(acc[3], al.w)
            FMA4(acc[4], ah.x) FMA4(acc[5], ah.y)
            FMA4(acc[6], ah.z) FMA4(acc[7], ah.w)
            #undef FMA4
        }

        #pragma unroll
        for (int rr = 0; rr < 8; ++rr) {
            int t = 8 * g + rr;
            float4 xv = *(const float4*)(xb + (size_t)t * NHW + ch * 128 + col);
            float4 o;
            o.x = fmaf(scale, acc[rr].x, xv.x);
            o.y = fmaf(scale, acc[rr].y, xv.y);
            o.z = fmaf(scale, acc[rr].z, xv.z);
            o.w = fmaf(scale, acc[rr].w, xv.w);
            *(float4*)(ob + (size_t)t * NHW + ch * 128 + col) = o;
        }
    }
}

// ---------------------------------------------------------------------------
extern "C" void kernel_launch(void* const* d_in, const int* in_sizes, int n_in,
                              void* d_out, int out_size, void* d_ws, size_t ws_size,
                              hipStream_t stream)
{
    const float* x       = (const float*)d_in[0];
    const float* y       = (const float*)d_in[1];
    const float* scale_p = (const float*)d_in[2];
    float* out = (float*)d_out;

    // Scratch: energy partials (1024 x 64 x 64 fp32 = 16.8 MB) live in d_out,
    // fully overwritten by k_out afterwards; attention (64 KB) lives in d_ws.
    float* part = out;
    float* att  = (float*)d_ws;

    k_energy <<<dim3(NB * NC * 2), 256, 0, stream>>>(x, y, part);
    k_softmax<<<dim3(NB * NT),     256, 0, stream>>>(part, att);
    k_out    <<<dim3(NB * NC * 2), 256, 0, stream>>>(x, y, att, scale_p, out);
}